// Round 5
// baseline (218.063 us; speedup 1.0000x reference)
//
#include <hip/hip_runtime.h>

#define OUT 7
#define NB 4        // batch
#define NC 256      // channels
#define NN 256      // rois per image
#define EPR (NC * OUT * OUT)   // 12544 elements per roi

typedef float nfloat4 __attribute__((ext_vector_type(4)));

// ---------------------------------------------------------------------------
// Kernel 1: fused transpose of ALL 5 FPN levels [B][C][P] -> [B][P][C].
// Flat blockIdx decoded to (level, p-tile, c-tile, batch). 32x32 tiles.
// Tile counts: L0 16384, L1 4096, L2 1024, L3 256, L4 64  -> 21824 blocks.
// ---------------------------------------------------------------------------
__global__ __launch_bounds__(256) void transpose_all(
    const float* __restrict__ f0, const float* __restrict__ f1,
    const float* __restrict__ f2, const float* __restrict__ f3,
    const float* __restrict__ f4, float* __restrict__ T)
{
    __shared__ float tile[32][33];
    const int bx = blockIdx.x;

    const float* in; float* outp; int P, t, shp;
    if (bx < 16384)      { in = f0; outp = T;            P = 16384; t = bx;         shp = 9; }
    else if (bx < 20480) { in = f1; outp = T + 16777216; P = 4096;  t = bx - 16384; shp = 7; }
    else if (bx < 21504) { in = f2; outp = T + 20971520; P = 1024;  t = bx - 20480; shp = 5; }
    else if (bx < 21760) { in = f3; outp = T + 22020096; P = 256;   t = bx - 21504; shp = 3; }
    else                 { in = f4; outp = T + 22282240; P = 64;    t = bx - 21760; shp = 1; }

    const int pt   = t & ((1 << shp) - 1);
    const int rest = t >> shp;
    const int ct   = rest & 7;
    const int b    = rest >> 3;
    const int p0   = pt << 5;
    const int c0   = ct << 5;
    const int tx   = threadIdx.x & 7;
    const int ty   = threadIdx.x >> 3;

    const float* src = in + ((size_t)((b << 8) + c0 + ty)) * P + p0 + (tx << 2);
    nfloat4 v = *(const nfloat4*)src;
    tile[ty][tx * 4 + 0] = v.x;
    tile[ty][tx * 4 + 1] = v.y;
    tile[ty][tx * 4 + 2] = v.z;
    tile[ty][tx * 4 + 3] = v.w;
    __syncthreads();

    nfloat4 w;
    w.x = tile[4 * tx + 0][ty];
    w.y = tile[4 * tx + 1][ty];
    w.z = tile[4 * tx + 2][ty];
    w.w = tile[4 * tx + 3][ty];
    float* dst = outp + ((size_t)b * P + p0 + ty) * NC + c0 + (tx << 2);
    *(nfloat4*)dst = w;
}

// ---------------------------------------------------------------------------
// Kernel 2: gather. grid (4, 1024): blockIdx.y = roi, blockIdx.x = 64-channel
// chunk. Thread t: channel = chunk*64 + (t&63); wave q = t>>6 handles output
// positions [q*49/4, (q+1)*49/4) -- wave-uniform bounds, no divergence.
// Every corner load = 64 consecutive channels = one 256B coalesced wave-load.
// LDS 12.5 KB -> 6 blocks/CU with launch_bounds(256,6).
// ---------------------------------------------------------------------------
__global__ __launch_bounds__(256, 6) void msroi_fast(
    const float* __restrict__ T, const float* __restrict__ rois,
    float* __restrict__ out)
{
    const int roi   = blockIdx.y;
    const int chunk = blockIdx.x;
    const int tid   = threadIdx.x;

    __shared__ float s_wyt[14], s_wyb[14], s_wxl[14], s_wxr[14];
    __shared__ int   s_yr0[14], s_yr1[14], s_x0[14], s_x1[14];
    __shared__ int   s_lvl;
    __shared__ __align__(16) float s_out[64 * 49];   // 12544 B

    if (tid < 28) {
        const float rx1 = rois[roi * 4 + 0];
        const float ry1 = rois[roi * 4 + 1];
        const float rx2 = rois[roi * 4 + 2];
        const float ry2 = rois[roi * 4 + 3];

        float area = (rx2 - rx1) * (ry2 - ry1);
        float lf = floorf(4.0f + log2f(sqrtf(area) / 224.0f + 1e-6f));
        lf = fminf(fmaxf(lf, 2.0f), 6.0f);
        int lvl = (int)lf - 2;
        if (tid == 0) s_lvl = lvl;

        float scale = 1.0f / (float)(4 << lvl);
        int   W     = 128 >> lvl;

        float x1 = rx1 * scale, y1 = ry1 * scale;
        float x2 = rx2 * scale, y2 = ry2 * scale;
        float rw = fmaxf(x2 - x1, 1.0f);
        float rh = fmaxf(y2 - y1, 1.0f);
        float bw = rw / (float)OUT;
        float bh = rh / (float)OUT;

        bool isx = (tid >= 14);
        int  g   = isx ? tid - 14 : tid;
        float gv = ((float)g + 0.5f) * 0.5f;
        float p  = isx ? (x1 + gv * bw) : (y1 + gv * bh);

        float v = (p >= -1.0f && p <= (float)W) ? 1.0f : 0.0f;
        float pc  = fminf(fmaxf(p, 0.0f), (float)(W - 1));
        float p0f = floorf(pc);
        int   p0  = (int)p0f;
        int   p1  = min(p0 + 1, W - 1);
        float l   = pc - p0f;

        if (isx) {
            s_x0[g] = p0; s_x1[g] = p1;
            s_wxl[g] = v * (1.0f - l); s_wxr[g] = v * l;
        } else {
            s_yr0[g] = p0 * W; s_yr1[g] = p1 * W;
            s_wyt[g] = v * (1.0f - l); s_wyb[g] = v * l;
        }
    }
    __syncthreads();

    const int lvl = s_lvl;
    const int W   = 128 >> lvl;
    const int POS = W * W;
    const int off_tab[5] = {0, 16777216, 20971520, 22020096, 22282240};
    const int b = roi >> 8;
    const int c = tid & 63;
    const int q = tid >> 6;
    const float* base = T + (size_t)off_tab[lvl]
                          + (size_t)b * POS * NC + (chunk << 6) + c;

    const int pstart = (q * 49) >> 2;          // {0,12,24,36}
    const int pend   = ((q + 1) * 49) >> 2;    // {12,24,36,49}

    for (int pos = pstart; pos < pend; ++pos) {
        const int oy = pos / 7;
        const int ox = pos - oy * 7;
        const int gy0 = oy * 2, gy1 = gy0 + 1;
        const int gx0 = ox * 2, gx1 = gx0 + 1;

        const float wt0 = s_wyt[gy0], wb0 = s_wyb[gy0];
        const float wt1 = s_wyt[gy1], wb1 = s_wyb[gy1];
        const int r00 = s_yr0[gy0], r01 = s_yr1[gy0];
        const int r10 = s_yr0[gy1], r11 = s_yr1[gy1];
        const float wl0 = s_wxl[gx0], wr0 = s_wxr[gx0];
        const float wl1 = s_wxl[gx1], wr1 = s_wxr[gx1];
        const int x00 = s_x0[gx0], x01 = s_x1[gx0];
        const int x10 = s_x0[gx1], x11 = s_x1[gx1];

        float acc;
        acc  = wt0 * (wl0 * base[(r00 + x00) << 8] + wr0 * base[(r00 + x01) << 8])
             + wb0 * (wl0 * base[(r01 + x00) << 8] + wr0 * base[(r01 + x01) << 8]);
        acc += wt0 * (wl1 * base[(r00 + x10) << 8] + wr1 * base[(r00 + x11) << 8])
             + wb0 * (wl1 * base[(r01 + x10) << 8] + wr1 * base[(r01 + x11) << 8]);
        acc += wt1 * (wl0 * base[(r10 + x00) << 8] + wr0 * base[(r10 + x01) << 8])
             + wb1 * (wl0 * base[(r11 + x00) << 8] + wr0 * base[(r11 + x01) << 8]);
        acc += wt1 * (wl1 * base[(r10 + x10) << 8] + wr1 * base[(r10 + x11) << 8])
             + wb1 * (wl1 * base[(r11 + x10) << 8] + wr1 * base[(r11 + x11) << 8]);

        s_out[c * 49 + pos] = acc * 0.25f;   // 49 ≡ 17 (mod 32): conflict-free
    }
    __syncthreads();

    // coalesced nontemporal store of this chunk's flat 12544-byte block
    float* ob = out + (size_t)roi * EPR + (chunk << 6) * 49;
    #pragma unroll
    for (int k = 0; k < 3; ++k) {
        const int i = tid + (k << 8);
        nfloat4 v = *(const nfloat4*)&s_out[i << 2];
        __builtin_nontemporal_store(v, (nfloat4*)&ob[i << 2]);
    }
    if (tid < 16) {
        const int i = tid + 768;
        nfloat4 v = *(const nfloat4*)&s_out[i << 2];
        __builtin_nontemporal_store(v, (nfloat4*)&ob[i << 2]);
    }
}

// ---------------------------------------------------------------------------
// Fallback (round-2 kernel) if workspace is too small for the transposed copy
// ---------------------------------------------------------------------------
__global__ __launch_bounds__(256) void msroi_kernel(
    const float* __restrict__ f0, const float* __restrict__ f1,
    const float* __restrict__ f2, const float* __restrict__ f3,
    const float* __restrict__ f4, const float* __restrict__ rois,
    float* __restrict__ out)
{
    const int roi = blockIdx.y;
    const int tid = threadIdx.x;

    __shared__ float s_wyt[14], s_wyb[14];
    __shared__ float s_wxl[14], s_wxr[14];
    __shared__ int   s_oy0[14], s_oy1[14];
    __shared__ int   s_x0[14],  s_x1[14];
    __shared__ int   s_lvl;

    if (tid < 28) {
        const float rx1 = rois[roi * 4 + 0];
        const float ry1 = rois[roi * 4 + 1];
        const float rx2 = rois[roi * 4 + 2];
        const float ry2 = rois[roi * 4 + 3];

        float area = (rx2 - rx1) * (ry2 - ry1);
        float lf = floorf(4.0f + log2f(sqrtf(area) / 224.0f + 1e-6f));
        lf = fminf(fmaxf(lf, 2.0f), 6.0f);
        int lvl = (int)lf - 2;
        if (tid == 0) s_lvl = lvl;

        float scale = 1.0f / (float)(4 << lvl);
        int   HW    = 128 >> lvl;

        float x1 = rx1 * scale, y1 = ry1 * scale;
        float x2 = rx2 * scale, y2 = ry2 * scale;
        float rw = fmaxf(x2 - x1, 1.0f);
        float rh = fmaxf(y2 - y1, 1.0f);
        float bw = rw / (float)OUT;
        float bh = rh / (float)OUT;

        bool isx = (tid >= 14);
        int  g   = isx ? tid - 14 : tid;
        float gv = ((float)g + 0.5f) * 0.5f;
        float p  = isx ? (x1 + gv * bw) : (y1 + gv * bh);

        float v = (p >= -1.0f && p <= (float)HW) ? 1.0f : 0.0f;
        float pc  = fminf(fmaxf(p, 0.0f), (float)(HW - 1));
        float p0f = floorf(pc);
        int   p0  = (int)p0f;
        int   p1  = min(p0 + 1, HW - 1);
        float l   = pc - p0f;

        if (isx) {
            s_x0[g] = p0; s_x1[g] = p1;
            s_wxl[g] = v * (1.0f - l); s_wxr[g] = v * l;
        } else {
            s_oy0[g] = p0 * HW; s_oy1[g] = p1 * HW;
            s_wyt[g] = v * (1.0f - l); s_wyb[g] = v * l;
        }
    }
    __syncthreads();

    const int lvl = s_lvl;
    const int HW  = 128 >> lvl;
    const int HW2 = HW * HW;
    const float* f = (lvl == 0) ? f0 : (lvl == 1) ? f1 : (lvl == 2) ? f2
                     : (lvl == 3) ? f3 : f4;
    const int b = roi >> 8;

    const int e0 = blockIdx.x * 512 + tid;

    float acc[2];
    #pragma unroll
    for (int k = 0; k < 2; ++k) {
        const int e  = e0 + k * 256;
        const int ec = (e < EPR) ? e : 0;
        const int c  = ec / 49;
        const int s  = ec - 49 * c;
        const int oy = s / 7;
        const int ox = s - 7 * oy;

        const float* fp = f + (size_t)(b * NC + c) * (size_t)HW2;

        float a = 0.0f;
        #pragma unroll
        for (int iy = 0; iy < 2; ++iy) {
            const int gy = oy * 2 + iy;
            const float wt = s_wyt[gy], wb = s_wyb[gy];
            const int   o0 = s_oy0[gy], o1 = s_oy1[gy];
            #pragma unroll
            for (int ix = 0; ix < 2; ++ix) {
                const int gx = ox * 2 + ix;
                const float wl = s_wxl[gx], wr = s_wxr[gx];
                const int   x0 = s_x0[gx],  x1i = s_x1[gx];
                const float v00 = fp[o0 + x0];
                const float v01 = fp[o0 + x1i];
                const float v10 = fp[o1 + x0];
                const float v11 = fp[o1 + x1i];
                a += (wt * wl) * v00 + (wt * wr) * v01
                   + (wb * wl) * v10 + (wb * wr) * v11;
            }
        }
        acc[k] = a * 0.25f;
    }

    #pragma unroll
    for (int k = 0; k < 2; ++k) {
        const int e = e0 + k * 256;
        if (e < EPR)
            __builtin_nontemporal_store(acc[k], &out[(size_t)roi * EPR + e]);
    }
}

extern "C" void kernel_launch(void* const* d_in, const int* in_sizes, int n_in,
                              void* d_out, int out_size, void* d_ws, size_t ws_size,
                              hipStream_t stream) {
    const float* f0   = (const float*)d_in[0];
    const float* f1   = (const float*)d_in[1];
    const float* f2   = (const float*)d_in[2];
    const float* f3   = (const float*)d_in[3];
    const float* f4   = (const float*)d_in[4];
    const float* rois = (const float*)d_in[5];
    float* out = (float*)d_out;

    const size_t need = 22347776ull * 4ull;   // 89.4 MB transposed features
    if (ws_size >= need) {
        float* T = (float*)d_ws;
        transpose_all<<<dim3(21824), dim3(256), 0, stream>>>(f0, f1, f2, f3, f4, T);
        msroi_fast<<<dim3(4, NB * NN), dim3(256), 0, stream>>>(T, rois, out);
    } else {
        dim3 grid((EPR + 511) / 512, NB * NN);
        dim3 block(256);
        msroi_kernel<<<grid, block, 0, stream>>>(f0, f1, f2, f3, f4, rois, out);
    }
}

// Round 6
// 194.758 us; speedup vs baseline: 1.1197x; 1.1197x over previous
//
#include <hip/hip_runtime.h>

#define OUT 7
#define NB 4        // batch
#define NC 256      // channels
#define NN 256      // rois per image
#define EPR (NC * OUT * OUT)   // 12544 elements per roi

typedef float nfloat4 __attribute__((ext_vector_type(4)));

// ---------------------------------------------------------------------------
// Kernel 1: fused transpose of ALL 5 FPN levels [B][C][P] -> [B][P][C].
// Flat blockIdx decoded to (level, p-tile, c-tile, batch). 32x32 tiles.
// Tile counts: L0 16384, L1 4096, L2 1024, L3 256, L4 64  -> 21824 blocks.
// ---------------------------------------------------------------------------
__global__ __launch_bounds__(256) void transpose_all(
    const float* __restrict__ f0, const float* __restrict__ f1,
    const float* __restrict__ f2, const float* __restrict__ f3,
    const float* __restrict__ f4, float* __restrict__ T)
{
    __shared__ float tile[32][33];
    const int bx = blockIdx.x;

    const float* in; float* outp; int P, t, shp;
    if (bx < 16384)      { in = f0; outp = T;            P = 16384; t = bx;         shp = 9; }
    else if (bx < 20480) { in = f1; outp = T + 16777216; P = 4096;  t = bx - 16384; shp = 7; }
    else if (bx < 21504) { in = f2; outp = T + 20971520; P = 1024;  t = bx - 20480; shp = 5; }
    else if (bx < 21760) { in = f3; outp = T + 22020096; P = 256;   t = bx - 21504; shp = 3; }
    else                 { in = f4; outp = T + 22282240; P = 64;    t = bx - 21760; shp = 1; }

    const int pt   = t & ((1 << shp) - 1);
    const int rest = t >> shp;
    const int ct   = rest & 7;
    const int b    = rest >> 3;
    const int p0   = pt << 5;
    const int c0   = ct << 5;
    const int tx   = threadIdx.x & 7;
    const int ty   = threadIdx.x >> 3;

    const float* src = in + ((size_t)((b << 8) + c0 + ty)) * P + p0 + (tx << 2);
    nfloat4 v = *(const nfloat4*)src;
    tile[ty][tx * 4 + 0] = v.x;
    tile[ty][tx * 4 + 1] = v.y;
    tile[ty][tx * 4 + 2] = v.z;
    tile[ty][tx * 4 + 3] = v.w;
    __syncthreads();

    nfloat4 w;
    w.x = tile[4 * tx + 0][ty];
    w.y = tile[4 * tx + 1][ty];
    w.z = tile[4 * tx + 2][ty];
    w.w = tile[4 * tx + 3][ty];
    float* dst = outp + ((size_t)b * P + p0 + ty) * NC + c0 + (tx << 2);
    *(nfloat4*)dst = w;
}

// ---------------------------------------------------------------------------
// Kernel 2: gather. One block per roi. Lane owns 4 consecutive channels
// (float4 loads -> 1KB per wave-load instruction, 16B/lane). Wave q handles
// positions q*13+i (i=0..12, clamped to 48 -> branch-free full unroll; the
// clamp only makes the same thread rewrite pos 48 with identical data).
// ---------------------------------------------------------------------------
__global__ __launch_bounds__(256, 3) void msroi_fast(
    const float* __restrict__ T, const float* __restrict__ rois,
    float* __restrict__ out)
{
    const int roi = blockIdx.x;
    const int tid = threadIdx.x;

    __shared__ float s_wyt[14], s_wyb[14], s_wxl[14], s_wxr[14];
    __shared__ int   s_yr0[14], s_yr1[14], s_x0[14], s_x1[14];
    __shared__ int   s_lvl;
    __shared__ __align__(16) float s_out[EPR];   // 50176 B

    if (tid < 28) {
        const float rx1 = rois[roi * 4 + 0];
        const float ry1 = rois[roi * 4 + 1];
        const float rx2 = rois[roi * 4 + 2];
        const float ry2 = rois[roi * 4 + 3];

        float area = (rx2 - rx1) * (ry2 - ry1);
        float lf = floorf(4.0f + log2f(sqrtf(area) / 224.0f + 1e-6f));
        lf = fminf(fmaxf(lf, 2.0f), 6.0f);
        int lvl = (int)lf - 2;
        if (tid == 0) s_lvl = lvl;

        float scale = 1.0f / (float)(4 << lvl);
        int   W     = 128 >> lvl;

        float x1 = rx1 * scale, y1 = ry1 * scale;
        float x2 = rx2 * scale, y2 = ry2 * scale;
        float rw = fmaxf(x2 - x1, 1.0f);
        float rh = fmaxf(y2 - y1, 1.0f);
        float bw = rw / (float)OUT;
        float bh = rh / (float)OUT;

        bool isx = (tid >= 14);
        int  g   = isx ? tid - 14 : tid;
        float gv = ((float)g + 0.5f) * 0.5f;
        float p  = isx ? (x1 + gv * bw) : (y1 + gv * bh);

        float v = (p >= -1.0f && p <= (float)W) ? 1.0f : 0.0f;
        float pc  = fminf(fmaxf(p, 0.0f), (float)(W - 1));
        float p0f = floorf(pc);
        int   p0  = (int)p0f;
        int   p1  = min(p0 + 1, W - 1);
        float l   = pc - p0f;

        if (isx) {
            s_x0[g] = p0; s_x1[g] = p1;
            s_wxl[g] = v * (1.0f - l); s_wxr[g] = v * l;
        } else {
            s_yr0[g] = p0 * W; s_yr1[g] = p1 * W;
            s_wyt[g] = v * (1.0f - l); s_wyb[g] = v * l;
        }
    }
    __syncthreads();

    const int lvl = s_lvl;
    const int W   = 128 >> lvl;
    const int POS = W * W;
    const int off_tab[5] = {0, 16777216, 20971520, 22020096, 22282240};
    const int b   = roi >> 8;
    const int q   = tid >> 6;          // wave id 0..3
    const int ch0 = (tid & 63) << 2;   // 4 channels per lane
    const float* base = T + (size_t)off_tab[lvl] + (size_t)b * POS * NC + ch0;

    #pragma unroll
    for (int i = 0; i < 13; ++i) {
        const int p  = min(q * 13 + i, 48);
        const int oy = p / 7;
        const int ox = p - oy * 7;
        const int gy0 = oy * 2, gy1 = gy0 + 1;
        const int gx0 = ox * 2, gx1 = gx0 + 1;

        const float wt0 = s_wyt[gy0], wb0 = s_wyb[gy0];
        const float wt1 = s_wyt[gy1], wb1 = s_wyb[gy1];
        const int r00 = s_yr0[gy0], r01 = s_yr1[gy0];
        const int r10 = s_yr0[gy1], r11 = s_yr1[gy1];
        const float wl0 = s_wxl[gx0], wr0 = s_wxr[gx0];
        const float wl1 = s_wxl[gx1], wr1 = s_wxr[gx1];
        const int x00 = s_x0[gx0], x01 = s_x1[gx0];
        const int x10 = s_x0[gx1], x11 = s_x1[gx1];

        const nfloat4 a00 = *(const nfloat4*)&base[(r00 + x00) << 8];
        const nfloat4 a01 = *(const nfloat4*)&base[(r00 + x01) << 8];
        const nfloat4 a02 = *(const nfloat4*)&base[(r01 + x00) << 8];
        const nfloat4 a03 = *(const nfloat4*)&base[(r01 + x01) << 8];
        const nfloat4 a04 = *(const nfloat4*)&base[(r00 + x10) << 8];
        const nfloat4 a05 = *(const nfloat4*)&base[(r00 + x11) << 8];
        const nfloat4 a06 = *(const nfloat4*)&base[(r01 + x10) << 8];
        const nfloat4 a07 = *(const nfloat4*)&base[(r01 + x11) << 8];
        const nfloat4 a08 = *(const nfloat4*)&base[(r10 + x00) << 8];
        const nfloat4 a09 = *(const nfloat4*)&base[(r10 + x01) << 8];
        const nfloat4 a10 = *(const nfloat4*)&base[(r11 + x00) << 8];
        const nfloat4 a11 = *(const nfloat4*)&base[(r11 + x01) << 8];
        const nfloat4 a12 = *(const nfloat4*)&base[(r10 + x10) << 8];
        const nfloat4 a13 = *(const nfloat4*)&base[(r10 + x11) << 8];
        const nfloat4 a14 = *(const nfloat4*)&base[(r11 + x10) << 8];
        const nfloat4 a15 = *(const nfloat4*)&base[(r11 + x11) << 8];

        nfloat4 acc;
        acc  = (wt0 * wl0) * a00 + (wt0 * wr0) * a01
             + (wb0 * wl0) * a02 + (wb0 * wr0) * a03;
        acc += (wt0 * wl1) * a04 + (wt0 * wr1) * a05
             + (wb0 * wl1) * a06 + (wb0 * wr1) * a07;
        acc += (wt1 * wl0) * a08 + (wt1 * wr0) * a09
             + (wb1 * wl0) * a10 + (wb1 * wr0) * a11;
        acc += (wt1 * wl1) * a12 + (wt1 * wr1) * a13
             + (wb1 * wl1) * a14 + (wb1 * wr1) * a15;
        acc *= 0.25f;

        s_out[(ch0 + 0) * 49 + p] = acc.x;
        s_out[(ch0 + 1) * 49 + p] = acc.y;
        s_out[(ch0 + 2) * 49 + p] = acc.z;
        s_out[(ch0 + 3) * 49 + p] = acc.w;
    }
    __syncthreads();

    // cooperative coalesced nontemporal store of the flat roi block
    float* ob = out + (size_t)roi * EPR;
    #pragma unroll
    for (int k = 0; k < 12; ++k) {
        const int f = (tid + (k << 8)) << 2;
        nfloat4 v = *(const nfloat4*)&s_out[f];
        __builtin_nontemporal_store(v, (nfloat4*)&ob[f]);
    }
    if (tid < 64) {
        const int f = (tid + 3072) << 2;
        nfloat4 v = *(const nfloat4*)&s_out[f];
        __builtin_nontemporal_store(v, (nfloat4*)&ob[f]);
    }
}

// ---------------------------------------------------------------------------
// Fallback (round-2 kernel) if workspace is too small for the transposed copy
// ---------------------------------------------------------------------------
__global__ __launch_bounds__(256) void msroi_kernel(
    const float* __restrict__ f0, const float* __restrict__ f1,
    const float* __restrict__ f2, const float* __restrict__ f3,
    const float* __restrict__ f4, const float* __restrict__ rois,
    float* __restrict__ out)
{
    const int roi = blockIdx.y;
    const int tid = threadIdx.x;

    __shared__ float s_wyt[14], s_wyb[14];
    __shared__ float s_wxl[14], s_wxr[14];
    __shared__ int   s_oy0[14], s_oy1[14];
    __shared__ int   s_x0[14],  s_x1[14];
    __shared__ int   s_lvl;

    if (tid < 28) {
        const float rx1 = rois[roi * 4 + 0];
        const float ry1 = rois[roi * 4 + 1];
        const float rx2 = rois[roi * 4 + 2];
        const float ry2 = rois[roi * 4 + 3];

        float area = (rx2 - rx1) * (ry2 - ry1);
        float lf = floorf(4.0f + log2f(sqrtf(area) / 224.0f + 1e-6f));
        lf = fminf(fmaxf(lf, 2.0f), 6.0f);
        int lvl = (int)lf - 2;
        if (tid == 0) s_lvl = lvl;

        float scale = 1.0f / (float)(4 << lvl);
        int   HW    = 128 >> lvl;

        float x1 = rx1 * scale, y1 = ry1 * scale;
        float x2 = rx2 * scale, y2 = ry2 * scale;
        float rw = fmaxf(x2 - x1, 1.0f);
        float rh = fmaxf(y2 - y1, 1.0f);
        float bw = rw / (float)OUT;
        float bh = rh / (float)OUT;

        bool isx = (tid >= 14);
        int  g   = isx ? tid - 14 : tid;
        float gv = ((float)g + 0.5f) * 0.5f;
        float p  = isx ? (x1 + gv * bw) : (y1 + gv * bh);

        float v = (p >= -1.0f && p <= (float)HW) ? 1.0f : 0.0f;
        float pc  = fminf(fmaxf(p, 0.0f), (float)(HW - 1));
        float p0f = floorf(pc);
        int   p0  = (int)p0f;
        int   p1  = min(p0 + 1, HW - 1);
        float l   = pc - p0f;

        if (isx) {
            s_x0[g] = p0; s_x1[g] = p1;
            s_wxl[g] = v * (1.0f - l); s_wxr[g] = v * l;
        } else {
            s_oy0[g] = p0 * HW; s_oy1[g] = p1 * HW;
            s_wyt[g] = v * (1.0f - l); s_wyb[g] = v * l;
        }
    }
    __syncthreads();

    const int lvl = s_lvl;
    const int HW  = 128 >> lvl;
    const int HW2 = HW * HW;
    const float* f = (lvl == 0) ? f0 : (lvl == 1) ? f1 : (lvl == 2) ? f2
                     : (lvl == 3) ? f3 : f4;
    const int b = roi >> 8;

    const int e0 = blockIdx.x * 512 + tid;

    float acc[2];
    #pragma unroll
    for (int k = 0; k < 2; ++k) {
        const int e  = e0 + k * 256;
        const int ec = (e < EPR) ? e : 0;
        const int c  = ec / 49;
        const int s  = ec - 49 * c;
        const int oy = s / 7;
        const int ox = s - 7 * oy;

        const float* fp = f + (size_t)(b * NC + c) * (size_t)HW2;

        float a = 0.0f;
        #pragma unroll
        for (int iy = 0; iy < 2; ++iy) {
            const int gy = oy * 2 + iy;
            const float wt = s_wyt[gy], wb = s_wyb[gy];
            const int   o0 = s_oy0[gy], o1 = s_oy1[gy];
            #pragma unroll
            for (int ix = 0; ix < 2; ++ix) {
                const int gx = ox * 2 + ix;
                const float wl = s_wxl[gx], wr = s_wxr[gx];
                const int   x0 = s_x0[gx],  x1i = s_x1[gx];
                const float v00 = fp[o0 + x0];
                const float v01 = fp[o0 + x1i];
                const float v10 = fp[o1 + x0];
                const float v11 = fp[o1 + x1i];
                a += (wt * wl) * v00 + (wt * wr) * v01
                   + (wb * wl) * v10 + (wb * wr) * v11;
            }
        }
        acc[k] = a * 0.25f;
    }

    #pragma unroll
    for (int k = 0; k < 2; ++k) {
        const int e = e0 + k * 256;
        if (e < EPR)
            __builtin_nontemporal_store(acc[k], &out[(size_t)roi * EPR + e]);
    }
}

extern "C" void kernel_launch(void* const* d_in, const int* in_sizes, int n_in,
                              void* d_out, int out_size, void* d_ws, size_t ws_size,
                              hipStream_t stream) {
    const float* f0   = (const float*)d_in[0];
    const float* f1   = (const float*)d_in[1];
    const float* f2   = (const float*)d_in[2];
    const float* f3   = (const float*)d_in[3];
    const float* f4   = (const float*)d_in[4];
    const float* rois = (const float*)d_in[5];
    float* out = (float*)d_out;

    const size_t need = 22347776ull * 4ull;   // 89.4 MB transposed features
    if (ws_size >= need) {
        float* T = (float*)d_ws;
        transpose_all<<<dim3(21824), dim3(256), 0, stream>>>(f0, f1, f2, f3, f4, T);
        msroi_fast<<<dim3(NB * NN), dim3(256), 0, stream>>>(T, rois, out);
    } else {
        dim3 grid((EPR + 511) / 512, NB * NN);
        dim3 block(256);
        msroi_kernel<<<grid, block, 0, stream>>>(f0, f1, f2, f3, f4, rois, out);
    }
}

// Round 7
// 171.196 us; speedup vs baseline: 1.2738x; 1.1376x over previous
//
#include <hip/hip_runtime.h>

#define OUT 7
#define NB 4        // batch
#define NC 256      // channels
#define NN 256      // rois per image
#define EPR (NC * OUT * OUT)   // 12544 elements per roi

typedef float nfloat4 __attribute__((ext_vector_type(4)));
typedef unsigned short nushort4 __attribute__((ext_vector_type(4)));

__device__ inline unsigned short f2bf(float f) {
    unsigned u = __builtin_bit_cast(unsigned, f);
    u += 0x7FFFu + ((u >> 16) & 1u);          // round-to-nearest-even
    return (unsigned short)(u >> 16);
}

__device__ inline nfloat4 bf4_to_f4(nushort4 s) {
    nfloat4 r;
    r.x = __builtin_bit_cast(float, (unsigned)s.x << 16);
    r.y = __builtin_bit_cast(float, (unsigned)s.y << 16);
    r.z = __builtin_bit_cast(float, (unsigned)s.z << 16);
    r.w = __builtin_bit_cast(float, (unsigned)s.w << 16);
    return r;
}

// ---------------------------------------------------------------------------
// Kernel 1: fused transpose of ALL 5 FPN levels [B][C][P] -> bf16 [B][P][C].
// Flat blockIdx decoded to (level, p-tile, c-tile, batch). 32x32 tiles.
// Tile counts: L0 16384, L1 4096, L2 1024, L3 256, L4 64  -> 21824 blocks.
// ---------------------------------------------------------------------------
__global__ __launch_bounds__(256) void transpose_all(
    const float* __restrict__ f0, const float* __restrict__ f1,
    const float* __restrict__ f2, const float* __restrict__ f3,
    const float* __restrict__ f4, unsigned short* __restrict__ T)
{
    __shared__ float tile[32][33];
    const int bx = blockIdx.x;

    const float* in; unsigned short* outp; int P, t, shp;
    if (bx < 16384)      { in = f0; outp = T;            P = 16384; t = bx;         shp = 9; }
    else if (bx < 20480) { in = f1; outp = T + 16777216; P = 4096;  t = bx - 16384; shp = 7; }
    else if (bx < 21504) { in = f2; outp = T + 20971520; P = 1024;  t = bx - 20480; shp = 5; }
    else if (bx < 21760) { in = f3; outp = T + 22020096; P = 256;   t = bx - 21504; shp = 3; }
    else                 { in = f4; outp = T + 22282240; P = 64;    t = bx - 21760; shp = 1; }

    const int pt   = t & ((1 << shp) - 1);
    const int rest = t >> shp;
    const int ct   = rest & 7;
    const int b    = rest >> 3;
    const int p0   = pt << 5;
    const int c0   = ct << 5;
    const int tx   = threadIdx.x & 7;
    const int ty   = threadIdx.x >> 3;

    const float* src = in + ((size_t)((b << 8) + c0 + ty)) * P + p0 + (tx << 2);
    nfloat4 v = *(const nfloat4*)src;
    tile[ty][tx * 4 + 0] = v.x;
    tile[ty][tx * 4 + 1] = v.y;
    tile[ty][tx * 4 + 2] = v.z;
    tile[ty][tx * 4 + 3] = v.w;
    __syncthreads();

    nushort4 w;
    w.x = f2bf(tile[4 * tx + 0][ty]);
    w.y = f2bf(tile[4 * tx + 1][ty]);
    w.z = f2bf(tile[4 * tx + 2][ty]);
    w.w = f2bf(tile[4 * tx + 3][ty]);
    unsigned short* dst = outp + ((size_t)b * P + p0 + ty) * NC + c0 + (tx << 2);
    *(nushort4*)dst = w;
}

// ---------------------------------------------------------------------------
// Kernel 2: gather. One block per roi. Lane owns 4 consecutive channels
// (ushort4 bf16 loads, 8B/lane -> 512B coalesced wave-loads). Wave q handles
// positions q*13+i (i=0..12, clamped to 48; clamp only makes the same thread
// rewrite pos 48 with identical data). Explicit 2-stage software pipeline:
// position i+1's 16 loads are in flight while position i is computed.
// ---------------------------------------------------------------------------
__global__ __launch_bounds__(256, 3) void msroi_fast(
    const unsigned short* __restrict__ T, const float* __restrict__ rois,
    float* __restrict__ out)
{
    const int roi = blockIdx.x;
    const int tid = threadIdx.x;

    __shared__ float s_wyt[14], s_wyb[14], s_wxl[14], s_wxr[14];
    __shared__ int   s_yr0[14], s_yr1[14], s_x0[14], s_x1[14];
    __shared__ int   s_lvl;
    __shared__ __align__(16) float s_out[EPR];   // 50176 B

    if (tid < 28) {
        const float rx1 = rois[roi * 4 + 0];
        const float ry1 = rois[roi * 4 + 1];
        const float rx2 = rois[roi * 4 + 2];
        const float ry2 = rois[roi * 4 + 3];

        float area = (rx2 - rx1) * (ry2 - ry1);
        float lf = floorf(4.0f + log2f(sqrtf(area) / 224.0f + 1e-6f));
        lf = fminf(fmaxf(lf, 2.0f), 6.0f);
        int lvl = (int)lf - 2;
        if (tid == 0) s_lvl = lvl;

        float scale = 1.0f / (float)(4 << lvl);
        int   W     = 128 >> lvl;

        float x1 = rx1 * scale, y1 = ry1 * scale;
        float x2 = rx2 * scale, y2 = ry2 * scale;
        float rw = fmaxf(x2 - x1, 1.0f);
        float rh = fmaxf(y2 - y1, 1.0f);
        float bw = rw / (float)OUT;
        float bh = rh / (float)OUT;

        bool isx = (tid >= 14);
        int  g   = isx ? tid - 14 : tid;
        float gv = ((float)g + 0.5f) * 0.5f;
        float p  = isx ? (x1 + gv * bw) : (y1 + gv * bh);

        float v = (p >= -1.0f && p <= (float)W) ? 1.0f : 0.0f;
        float pc  = fminf(fmaxf(p, 0.0f), (float)(W - 1));
        float p0f = floorf(pc);
        int   p0  = (int)p0f;
        int   p1  = min(p0 + 1, W - 1);
        float l   = pc - p0f;

        if (isx) {
            s_x0[g] = p0; s_x1[g] = p1;
            s_wxl[g] = v * (1.0f - l); s_wxr[g] = v * l;
        } else {
            s_yr0[g] = p0 * W; s_yr1[g] = p1 * W;
            s_wyt[g] = v * (1.0f - l); s_wyb[g] = v * l;
        }
    }
    __syncthreads();

    const int lvl = s_lvl;
    const int W   = 128 >> lvl;
    const int POS = W * W;
    const int off_tab[5] = {0, 16777216, 20971520, 22020096, 22282240};
    const int b   = roi >> 8;
    const int q   = tid >> 6;          // wave id 0..3
    const int ch0 = (tid & 63) << 2;   // 4 channels per lane
    const unsigned short* base =
        T + (size_t)off_tab[lvl] + (size_t)b * POS * NC + ch0;

    // gather corner offsets + weights for one output position
    auto make_pos = [&](int p, int* off, float* w) {
        const int oy = p / 7;
        const int ox = p - oy * 7;
        const int gy0 = oy * 2, gy1 = gy0 + 1;
        const int gx0 = ox * 2, gx1 = gx0 + 1;
        const float wt0 = s_wyt[gy0], wb0 = s_wyb[gy0];
        const float wt1 = s_wyt[gy1], wb1 = s_wyb[gy1];
        const int r00 = s_yr0[gy0], r01 = s_yr1[gy0];
        const int r10 = s_yr0[gy1], r11 = s_yr1[gy1];
        const float wl0 = s_wxl[gx0], wr0 = s_wxr[gx0];
        const float wl1 = s_wxl[gx1], wr1 = s_wxr[gx1];
        const int x00 = s_x0[gx0], x01 = s_x1[gx0];
        const int x10 = s_x0[gx1], x11 = s_x1[gx1];
        off[0]  = r00 + x00; w[0]  = wt0 * wl0;
        off[1]  = r00 + x01; w[1]  = wt0 * wr0;
        off[2]  = r01 + x00; w[2]  = wb0 * wl0;
        off[3]  = r01 + x01; w[3]  = wb0 * wr0;
        off[4]  = r00 + x10; w[4]  = wt0 * wl1;
        off[5]  = r00 + x11; w[5]  = wt0 * wr1;
        off[6]  = r01 + x10; w[6]  = wb0 * wl1;
        off[7]  = r01 + x11; w[7]  = wb0 * wr1;
        off[8]  = r10 + x00; w[8]  = wt1 * wl0;
        off[9]  = r10 + x01; w[9]  = wt1 * wr0;
        off[10] = r11 + x00; w[10] = wb1 * wl0;
        off[11] = r11 + x01; w[11] = wb1 * wr0;
        off[12] = r10 + x10; w[12] = wt1 * wl1;
        off[13] = r10 + x11; w[13] = wt1 * wr1;
        off[14] = r11 + x10; w[14] = wb1 * wl1;
        off[15] = r11 + x11; w[15] = wb1 * wr1;
    };

    int p_cur = min(q * 13, 48);
    int offA[16]; float wA[16];
    nushort4 L[16];
    make_pos(p_cur, offA, wA);
    #pragma unroll
    for (int k = 0; k < 16; ++k)
        L[k] = *(const nushort4*)&base[(size_t)offA[k] << 8];

    #pragma unroll
    for (int i = 0; i < 13; ++i) {
        const int p_nxt = min(q * 13 + i + 1, 48);
        int offB[16]; float wB[16];
        nushort4 M[16];
        if (i < 12) {
            make_pos(p_nxt, offB, wB);
            #pragma unroll
            for (int k = 0; k < 16; ++k)
                M[k] = *(const nushort4*)&base[(size_t)offB[k] << 8];
        }

        nfloat4 acc = {0.0f, 0.0f, 0.0f, 0.0f};
        #pragma unroll
        for (int k = 0; k < 16; ++k)
            acc += wA[k] * bf4_to_f4(L[k]);
        acc *= 0.25f;

        s_out[(ch0 + 0) * 49 + p_cur] = acc.x;
        s_out[(ch0 + 1) * 49 + p_cur] = acc.y;
        s_out[(ch0 + 2) * 49 + p_cur] = acc.z;
        s_out[(ch0 + 3) * 49 + p_cur] = acc.w;

        #pragma unroll
        for (int k = 0; k < 16; ++k) { L[k] = M[k]; wA[k] = wB[k]; }
        p_cur = p_nxt;
    }
    __syncthreads();

    // cooperative coalesced nontemporal store of the flat roi block
    float* ob = out + (size_t)roi * EPR;
    #pragma unroll
    for (int k = 0; k < 12; ++k) {
        const int f = (tid + (k << 8)) << 2;
        nfloat4 v = *(const nfloat4*)&s_out[f];
        __builtin_nontemporal_store(v, (nfloat4*)&ob[f]);
    }
    if (tid < 64) {
        const int f = (tid + 3072) << 2;
        nfloat4 v = *(const nfloat4*)&s_out[f];
        __builtin_nontemporal_store(v, (nfloat4*)&ob[f]);
    }
}

// ---------------------------------------------------------------------------
// Fallback (round-2 kernel, fp32 direct) if workspace is too small
// ---------------------------------------------------------------------------
__global__ __launch_bounds__(256) void msroi_kernel(
    const float* __restrict__ f0, const float* __restrict__ f1,
    const float* __restrict__ f2, const float* __restrict__ f3,
    const float* __restrict__ f4, const float* __restrict__ rois,
    float* __restrict__ out)
{
    const int roi = blockIdx.y;
    const int tid = threadIdx.x;

    __shared__ float s_wyt[14], s_wyb[14];
    __shared__ float s_wxl[14], s_wxr[14];
    __shared__ int   s_oy0[14], s_oy1[14];
    __shared__ int   s_x0[14],  s_x1[14];
    __shared__ int   s_lvl;

    if (tid < 28) {
        const float rx1 = rois[roi * 4 + 0];
        const float ry1 = rois[roi * 4 + 1];
        const float rx2 = rois[roi * 4 + 2];
        const float ry2 = rois[roi * 4 + 3];

        float area = (rx2 - rx1) * (ry2 - ry1);
        float lf = floorf(4.0f + log2f(sqrtf(area) / 224.0f + 1e-6f));
        lf = fminf(fmaxf(lf, 2.0f), 6.0f);
        int lvl = (int)lf - 2;
        if (tid == 0) s_lvl = lvl;

        float scale = 1.0f / (float)(4 << lvl);
        int   HW    = 128 >> lvl;

        float x1 = rx1 * scale, y1 = ry1 * scale;
        float x2 = rx2 * scale, y2 = ry2 * scale;
        float rw = fmaxf(x2 - x1, 1.0f);
        float rh = fmaxf(y2 - y1, 1.0f);
        float bw = rw / (float)OUT;
        float bh = rh / (float)OUT;

        bool isx = (tid >= 14);
        int  g   = isx ? tid - 14 : tid;
        float gv = ((float)g + 0.5f) * 0.5f;
        float p  = isx ? (x1 + gv * bw) : (y1 + gv * bh);

        float v = (p >= -1.0f && p <= (float)HW) ? 1.0f : 0.0f;
        float pc  = fminf(fmaxf(p, 0.0f), (float)(HW - 1));
        float p0f = floorf(pc);
        int   p0  = (int)p0f;
        int   p1  = min(p0 + 1, HW - 1);
        float l   = pc - p0f;

        if (isx) {
            s_x0[g] = p0; s_x1[g] = p1;
            s_wxl[g] = v * (1.0f - l); s_wxr[g] = v * l;
        } else {
            s_oy0[g] = p0 * HW; s_oy1[g] = p1 * HW;
            s_wyt[g] = v * (1.0f - l); s_wyb[g] = v * l;
        }
    }
    __syncthreads();

    const int lvl = s_lvl;
    const int HW  = 128 >> lvl;
    const int HW2 = HW * HW;
    const float* f = (lvl == 0) ? f0 : (lvl == 1) ? f1 : (lvl == 2) ? f2
                     : (lvl == 3) ? f3 : f4;
    const int b = roi >> 8;

    const int e0 = blockIdx.x * 512 + tid;

    float acc[2];
    #pragma unroll
    for (int k = 0; k < 2; ++k) {
        const int e  = e0 + k * 256;
        const int ec = (e < EPR) ? e : 0;
        const int c  = ec / 49;
        const int s  = ec - 49 * c;
        const int oy = s / 7;
        const int ox = s - 7 * oy;

        const float* fp = f + (size_t)(b * NC + c) * (size_t)HW2;

        float a = 0.0f;
        #pragma unroll
        for (int iy = 0; iy < 2; ++iy) {
            const int gy = oy * 2 + iy;
            const float wt = s_wyt[gy], wb = s_wyb[gy];
            const int   o0 = s_oy0[gy], o1 = s_oy1[gy];
            #pragma unroll
            for (int ix = 0; ix < 2; ++ix) {
                const int gx = ox * 2 + ix;
                const float wl = s_wxl[gx], wr = s_wxr[gx];
                const int   x0 = s_x0[gx],  x1i = s_x1[gx];
                const float v00 = fp[o0 + x0];
                const float v01 = fp[o0 + x1i];
                const float v10 = fp[o1 + x0];
                const float v11 = fp[o1 + x1i];
                a += (wt * wl) * v00 + (wt * wr) * v01
                   + (wb * wl) * v10 + (wb * wr) * v11;
            }
        }
        acc[k] = a * 0.25f;
    }

    #pragma unroll
    for (int k = 0; k < 2; ++k) {
        const int e = e0 + k * 256;
        if (e < EPR)
            __builtin_nontemporal_store(acc[k], &out[(size_t)roi * EPR + e]);
    }
}

extern "C" void kernel_launch(void* const* d_in, const int* in_sizes, int n_in,
                              void* d_out, int out_size, void* d_ws, size_t ws_size,
                              hipStream_t stream) {
    const float* f0   = (const float*)d_in[0];
    const float* f1   = (const float*)d_in[1];
    const float* f2   = (const float*)d_in[2];
    const float* f3   = (const float*)d_in[3];
    const float* f4   = (const float*)d_in[4];
    const float* rois = (const float*)d_in[5];
    float* out = (float*)d_out;

    const size_t need = 22347776ull * 2ull;   // 44.7 MB bf16 transposed features
    if (ws_size >= need) {
        unsigned short* T = (unsigned short*)d_ws;
        transpose_all<<<dim3(21824), dim3(256), 0, stream>>>(f0, f1, f2, f3, f4, T);
        msroi_fast<<<dim3(NB * NN), dim3(256), 0, stream>>>(T, rois, out);
    } else {
        dim3 grid((EPR + 511) / 512, NB * NN);
        dim3 block(256);
        msroi_kernel<<<grid, block, 0, stream>>>(f0, f1, f2, f3, f4, rois, out);
    }
}

// Round 8
// 162.939 us; speedup vs baseline: 1.3383x; 1.0507x over previous
//
#include <hip/hip_runtime.h>

#define OUT 7
#define NB 4        // batch
#define NC 256      // channels
#define NN 256      // rois per image
#define EPR (NC * OUT * OUT)   // 12544 elements per roi

typedef float nfloat4 __attribute__((ext_vector_type(4)));
typedef unsigned short nushort4 __attribute__((ext_vector_type(4)));
typedef unsigned short nushort2 __attribute__((ext_vector_type(2)));

__device__ inline unsigned short f2bf(float f) {
    unsigned u = __builtin_bit_cast(unsigned, f);
    u += 0x7FFFu + ((u >> 16) & 1u);          // round-to-nearest-even
    return (unsigned short)(u >> 16);
}

__device__ inline float bf2f(unsigned short s) {
    return __builtin_bit_cast(float, (unsigned)s << 16);
}

// ---------------------------------------------------------------------------
// Kernel 1: fused transpose of ALL 5 FPN levels [B][C][P] -> bf16 [B][P][C].
// Each block: 32 p x 128 c macro-tile (4 c-tiles sequentially through one LDS
// tile). Nontemporal fp32 loads (read-once), cached bf16 stores (re-read by
// the gather). 5456 blocks.
// ---------------------------------------------------------------------------
__global__ __launch_bounds__(256) void transpose_all(
    const float* __restrict__ f0, const float* __restrict__ f1,
    const float* __restrict__ f2, const float* __restrict__ f3,
    const float* __restrict__ f4, unsigned short* __restrict__ T)
{
    __shared__ float tile[32][33];
    const int bx = blockIdx.x;

    const float* in; unsigned short* outp; int P, t, shp;
    if (bx < 4096)      { in = f0; outp = T;            P = 16384; t = bx;        shp = 9; }
    else if (bx < 5120) { in = f1; outp = T + 16777216; P = 4096;  t = bx - 4096; shp = 7; }
    else if (bx < 5376) { in = f2; outp = T + 20971520; P = 1024;  t = bx - 5120; shp = 5; }
    else if (bx < 5440) { in = f3; outp = T + 22020096; P = 256;   t = bx - 5376; shp = 3; }
    else                { in = f4; outp = T + 22282240; P = 64;    t = bx - 5440; shp = 1; }

    const int pt   = t & ((1 << shp) - 1);
    const int rest = t >> shp;
    const int cm   = rest & 1;      // c-macro: 0 -> ch 0..127, 1 -> 128..255
    const int b    = rest >> 1;
    const int p0   = pt << 5;
    const int tx   = threadIdx.x & 7;
    const int ty   = threadIdx.x >> 3;

    #pragma unroll
    for (int ct = 0; ct < 4; ++ct) {
        const int c0 = (cm << 7) + (ct << 5);
        const float* src = in + ((size_t)((b << 8) + c0 + ty)) * P + p0 + (tx << 2);
        nfloat4 v = __builtin_nontemporal_load((const nfloat4*)src);
        tile[ty][tx * 4 + 0] = v.x;
        tile[ty][tx * 4 + 1] = v.y;
        tile[ty][tx * 4 + 2] = v.z;
        tile[ty][tx * 4 + 3] = v.w;
        __syncthreads();

        nushort4 w;
        w.x = f2bf(tile[4 * tx + 0][ty]);
        w.y = f2bf(tile[4 * tx + 1][ty]);
        w.z = f2bf(tile[4 * tx + 2][ty]);
        w.w = f2bf(tile[4 * tx + 3][ty]);
        unsigned short* dst = outp + ((size_t)b * P + p0 + ty) * NC + c0 + (tx << 2);
        *(nushort4*)dst = w;
        __syncthreads();
    }
}

// ---------------------------------------------------------------------------
// Kernel 2: gather. grid 2048: blockIdx>>1 = roi, blockIdx&1 = 128-channel
// half. Lane owns 2 consecutive channels (ushort2 bf16 -> 256B coalesced
// wave-loads on disjoint half-lines). Wave q handles positions q*13+i
// (i=0..12, clamp 48 = same-thread benign rewrite). 2-stage pipeline:
// next position's 16 loads in flight during current compute; weights
// recomputed from LDS in the compute stage to keep VGPR < 102.
// LDS 25 KB -> 5 blocks/CU with launch_bounds(256,5).
// ---------------------------------------------------------------------------
__global__ __launch_bounds__(256, 5) void msroi_fast(
    const unsigned short* __restrict__ T, const float* __restrict__ rois,
    float* __restrict__ out)
{
    const int roi   = blockIdx.x >> 1;
    const int chunk = blockIdx.x & 1;
    const int tid   = threadIdx.x;

    __shared__ float s_wy[2][14];   // [0]=vy*(1-ly), [1]=vy*ly
    __shared__ float s_wx[2][14];   // [0]=vx*(1-lx), [1]=vx*lx
    __shared__ int   s_yr[2][14];   // y0*W, y1*W
    __shared__ int   s_xc[2][14];   // x0, x1
    __shared__ int   s_lvl;
    __shared__ __align__(16) float s_out[128 * 49];   // 25088 B

    if (tid < 28) {
        const float rx1 = rois[roi * 4 + 0];
        const float ry1 = rois[roi * 4 + 1];
        const float rx2 = rois[roi * 4 + 2];
        const float ry2 = rois[roi * 4 + 3];

        float area = (rx2 - rx1) * (ry2 - ry1);
        float lf = floorf(4.0f + log2f(sqrtf(area) / 224.0f + 1e-6f));
        lf = fminf(fmaxf(lf, 2.0f), 6.0f);
        int lvl = (int)lf - 2;
        if (tid == 0) s_lvl = lvl;

        float scale = 1.0f / (float)(4 << lvl);
        int   W     = 128 >> lvl;

        float x1 = rx1 * scale, y1 = ry1 * scale;
        float x2 = rx2 * scale, y2 = ry2 * scale;
        float rw = fmaxf(x2 - x1, 1.0f);
        float rh = fmaxf(y2 - y1, 1.0f);
        float bw = rw / (float)OUT;
        float bh = rh / (float)OUT;

        bool isx = (tid >= 14);
        int  g   = isx ? tid - 14 : tid;
        float gv = ((float)g + 0.5f) * 0.5f;
        float p  = isx ? (x1 + gv * bw) : (y1 + gv * bh);

        float v = (p >= -1.0f && p <= (float)W) ? 1.0f : 0.0f;
        float pc  = fminf(fmaxf(p, 0.0f), (float)(W - 1));
        float p0f = floorf(pc);
        int   p0  = (int)p0f;
        int   p1  = min(p0 + 1, W - 1);
        float l   = pc - p0f;

        if (isx) {
            s_xc[0][g] = p0; s_xc[1][g] = p1;
            s_wx[0][g] = v * (1.0f - l); s_wx[1][g] = v * l;
        } else {
            s_yr[0][g] = p0 * W; s_yr[1][g] = p1 * W;
            s_wy[0][g] = v * (1.0f - l); s_wy[1][g] = v * l;
        }
    }
    __syncthreads();

    const int lvl = s_lvl;
    const int W   = 128 >> lvl;
    const int POS = W * W;
    const int off_tab[5] = {0, 16777216, 20971520, 22020096, 22282240};
    const int b    = roi >> 8;
    const int q    = tid >> 6;          // wave id 0..3
    const int cl   = (tid & 63) << 1;   // local channel 0..126 (2 per lane)
    const unsigned short* base =
        T + (size_t)off_tab[lvl] + (size_t)b * POS * NC + (chunk << 7) + cl;

    // 16 corner element-offsets for one output position (addresses only)
    auto make_off = [&](int p, int* off) {
        const int oy = p / 7;
        const int ox = p - oy * 7;
        const int R[4] = { s_yr[0][2 * oy],     s_yr[1][2 * oy],
                           s_yr[0][2 * oy + 1], s_yr[1][2 * oy + 1] };
        const int C[4] = { s_xc[0][2 * ox],     s_xc[1][2 * ox],
                           s_xc[0][2 * ox + 1], s_xc[1][2 * ox + 1] };
        #pragma unroll
        for (int a = 0; a < 4; ++a)
            #pragma unroll
            for (int c2 = 0; c2 < 4; ++c2)
                off[a * 4 + c2] = R[a] + C[c2];
    };

    int p_cur = min(q * 13, 48);
    int offA[16];
    nushort2 L[16], M[16];
    make_off(p_cur, offA);
    #pragma unroll
    for (int k = 0; k < 16; ++k)
        L[k] = *(const nushort2*)&base[(size_t)offA[k] << 8];

    #pragma unroll
    for (int i = 0; i < 13; ++i) {
        const int p_nxt = min(q * 13 + i + 1, 48);
        if (i < 12) {
            int offB[16];
            make_off(p_nxt, offB);
            #pragma unroll
            for (int k = 0; k < 16; ++k)
                M[k] = *(const nushort2*)&base[(size_t)offB[k] << 8];
        }

        // weights for current position (recomputed from LDS -> low VGPR)
        const int oy = p_cur / 7;
        const int ox = p_cur - oy * 7;
        const float WY[4] = { s_wy[0][2 * oy],     s_wy[1][2 * oy],
                              s_wy[0][2 * oy + 1], s_wy[1][2 * oy + 1] };
        const float WX[4] = { s_wx[0][2 * ox],     s_wx[1][2 * ox],
                              s_wx[0][2 * ox + 1], s_wx[1][2 * ox + 1] };

        float a0 = 0.0f, a1 = 0.0f;
        #pragma unroll
        for (int k = 0; k < 16; ++k) {
            const float w = WY[k >> 2] * WX[k & 3];
            a0 += w * bf2f(L[k].x);
            a1 += w * bf2f(L[k].y);
        }

        s_out[(cl + 0) * 49 + p_cur] = a0 * 0.25f;
        s_out[(cl + 1) * 49 + p_cur] = a1 * 0.25f;

        #pragma unroll
        for (int k = 0; k < 16; ++k) L[k] = M[k];
        p_cur = p_nxt;
    }
    __syncthreads();

    // cooperative coalesced nontemporal store: 6272 floats = 1568 float4
    float* ob = out + (size_t)roi * EPR + (chunk << 7) * 49;
    #pragma unroll
    for (int k = 0; k < 6; ++k) {
        const int f = (tid + (k << 8)) << 2;
        nfloat4 v = *(const nfloat4*)&s_out[f];
        __builtin_nontemporal_store(v, (nfloat4*)&ob[f]);
    }
    if (tid < 32) {
        const int f = (tid + 1536) << 2;
        nfloat4 v = *(const nfloat4*)&s_out[f];
        __builtin_nontemporal_store(v, (nfloat4*)&ob[f]);
    }
}

// ---------------------------------------------------------------------------
// Fallback (round-2 kernel, fp32 direct) if workspace is too small
// ---------------------------------------------------------------------------
__global__ __launch_bounds__(256) void msroi_kernel(
    const float* __restrict__ f0, const float* __restrict__ f1,
    const float* __restrict__ f2, const float* __restrict__ f3,
    const float* __restrict__ f4, const float* __restrict__ rois,
    float* __restrict__ out)
{
    const int roi = blockIdx.y;
    const int tid = threadIdx.x;

    __shared__ float s_wyt[14], s_wyb[14];
    __shared__ float s_wxl[14], s_wxr[14];
    __shared__ int   s_oy0[14], s_oy1[14];
    __shared__ int   s_x0[14],  s_x1[14];
    __shared__ int   s_lvl;

    if (tid < 28) {
        const float rx1 = rois[roi * 4 + 0];
        const float ry1 = rois[roi * 4 + 1];
        const float rx2 = rois[roi * 4 + 2];
        const float ry2 = rois[roi * 4 + 3];

        float area = (rx2 - rx1) * (ry2 - ry1);
        float lf = floorf(4.0f + log2f(sqrtf(area) / 224.0f + 1e-6f));
        lf = fminf(fmaxf(lf, 2.0f), 6.0f);
        int lvl = (int)lf - 2;
        if (tid == 0) s_lvl = lvl;

        float scale = 1.0f / (float)(4 << lvl);
        int   HW    = 128 >> lvl;

        float x1 = rx1 * scale, y1 = ry1 * scale;
        float x2 = rx2 * scale, y2 = ry2 * scale;
        float rw = fmaxf(x2 - x1, 1.0f);
        float rh = fmaxf(y2 - y1, 1.0f);
        float bw = rw / (float)OUT;
        float bh = rh / (float)OUT;

        bool isx = (tid >= 14);
        int  g   = isx ? tid - 14 : tid;
        float gv = ((float)g + 0.5f) * 0.5f;
        float p  = isx ? (x1 + gv * bw) : (y1 + gv * bh);

        float v = (p >= -1.0f && p <= (float)HW) ? 1.0f : 0.0f;
        float pc  = fminf(fmaxf(p, 0.0f), (float)(HW - 1));
        float p0f = floorf(pc);
        int   p0  = (int)p0f;
        int   p1  = min(p0 + 1, HW - 1);
        float l   = pc - p0f;

        if (isx) {
            s_x0[g] = p0; s_x1[g] = p1;
            s_wxl[g] = v * (1.0f - l); s_wxr[g] = v * l;
        } else {
            s_oy0[g] = p0 * HW; s_oy1[g] = p1 * HW;
            s_wyt[g] = v * (1.0f - l); s_wyb[g] = v * l;
        }
    }
    __syncthreads();

    const int lvl = s_lvl;
    const int HW  = 128 >> lvl;
    const int HW2 = HW * HW;
    const float* f = (lvl == 0) ? f0 : (lvl == 1) ? f1 : (lvl == 2) ? f2
                     : (lvl == 3) ? f3 : f4;
    const int b = roi >> 8;

    const int e0 = blockIdx.x * 512 + tid;

    float acc[2];
    #pragma unroll
    for (int k = 0; k < 2; ++k) {
        const int e  = e0 + k * 256;
        const int ec = (e < EPR) ? e : 0;
        const int c  = ec / 49;
        const int s  = ec - 49 * c;
        const int oy = s / 7;
        const int ox = s - 7 * oy;

        const float* fp = f + (size_t)(b * NC + c) * (size_t)HW2;

        float a = 0.0f;
        #pragma unroll
        for (int iy = 0; iy < 2; ++iy) {
            const int gy = oy * 2 + iy;
            const float wt = s_wyt[gy], wb = s_wyb[gy];
            const int   o0 = s_oy0[gy], o1 = s_oy1[gy];
            #pragma unroll
            for (int ix = 0; ix < 2; ++ix) {
                const int gx = ox * 2 + ix;
                const float wl = s_wxl[gx], wr = s_wxr[gx];
                const int   x0 = s_x0[gx],  x1i = s_x1[gx];
                const float v00 = fp[o0 + x0];
                const float v01 = fp[o0 + x1i];
                const float v10 = fp[o1 + x0];
                const float v11 = fp[o1 + x1i];
                a += (wt * wl) * v00 + (wt * wr) * v01
                   + (wb * wl) * v10 + (wb * wr) * v11;
            }
        }
        acc[k] = a * 0.25f;
    }

    #pragma unroll
    for (int k = 0; k < 2; ++k) {
        const int e = e0 + k * 256;
        if (e < EPR)
            __builtin_nontemporal_store(acc[k], &out[(size_t)roi * EPR + e]);
    }
}

extern "C" void kernel_launch(void* const* d_in, const int* in_sizes, int n_in,
                              void* d_out, int out_size, void* d_ws, size_t ws_size,
                              hipStream_t stream) {
    const float* f0   = (const float*)d_in[0];
    const float* f1   = (const float*)d_in[1];
    const float* f2   = (const float*)d_in[2];
    const float* f3   = (const float*)d_in[3];
    const float* f4   = (const float*)d_in[4];
    const float* rois = (const float*)d_in[5];
    float* out = (float*)d_out;

    const size_t need = 22347776ull * 2ull;   // 44.7 MB bf16 transposed features
    if (ws_size >= need) {
        unsigned short* T = (unsigned short*)d_ws;
        transpose_all<<<dim3(5456), dim3(256), 0, stream>>>(f0, f1, f2, f3, f4, T);
        msroi_fast<<<dim3(NB * NN * 2), dim3(256), 0, stream>>>(T, rois, out);
    } else {
        dim3 grid((EPR + 511) / 512, NB * NN);
        dim3 block(256);
        msroi_kernel<<<grid, block, 0, stream>>>(f0, f1, f2, f3, f4, rois, out);
    }
}